// Round 8
// baseline (1083.733 us; speedup 1.0000x reference)
//
#include <hip/hip_runtime.h>
#include <stdint.h>

typedef unsigned short u16;
typedef unsigned int   u32;
typedef float f32x4  __attribute__((ext_vector_type(4)));
typedef _Float16 f16x4 __attribute__((ext_vector_type(4)));
typedef _Float16 f16x8 __attribute__((ext_vector_type(8)));

#define NN0 200000
#define NN1 100000
#define NN2 50000
#define EE0 1600000
#define EE1 800000
#define DD  256
#define CC  7
#define KK  40
#define NHEAD 288               // 7 scores + 280 proj + 1 pad col

// fp16 2-level split-weight image geometry:
// per (ntile, chunk): 2 levels x 128 rows x 32 fp16 = 16384 B, XOR-swizzled
// swizzle: 16-B quad q (k>>3) stored at q ^ ((row>>1)&3)  -> conflict-free b128 r/w
#define LVL2_U16 4096           // u16 per level (128 rows x 32)
#define IMG_U16  8192           // u16 per chunk image (2 levels)

// ---------------- split f32 -> 2 fp16 (residual) ----------------
static __device__ __forceinline__ void split2(float x, _Float16& t0, _Float16& t1) {
    t0 = (_Float16)x;
    t1 = (_Float16)(x - (float)t0);
}

static __device__ __forceinline__ f16x8 pack8(const _Float16* h) {
    f16x8 v;
#pragma unroll
    for (int i = 0; i < 8; ++i) v[i] = h[i];
    return v;
}

static __device__ __forceinline__ void async16(const void* g, void* l) {
    __builtin_amdgcn_global_load_lds(
        (const __attribute__((address_space(1))) void*)g,
        (__attribute__((address_space(3))) void*)l, 16, 0, 0);
}

static __device__ __forceinline__ void loadA_f32(const float* p, float* xa) {
#pragma unroll
    for (int j = 0; j < 16; j += 4) {
        float4 v = *reinterpret_cast<const float4*>(p + j);
        xa[j] = v.x; xa[j + 1] = v.y; xa[j + 2] = v.z; xa[j + 3] = v.w;
    }
}

static __device__ __forceinline__ void writeA_f32(const float* xa, u16* d, int q0, int q1) {
    _Float16 h0[16], h1v[16];
#pragma unroll
    for (int j = 0; j < 16; ++j) split2(xa[j], h0[j], h1v[j]);
    *reinterpret_cast<f16x8*>(d + q0 * 8)            = pack8(h0);
    *reinterpret_cast<f16x8*>(d + q1 * 8)            = pack8(h0 + 8);
    *reinterpret_cast<f16x8*>(d + LVL2_U16 + q0 * 8) = pack8(h1v);
    *reinterpret_cast<f16x8*>(d + LVL2_U16 + q1 * 8) = pack8(h1v + 8);
}

// ---------------- histogram ----------------
__global__ void hist_kernel(const int* __restrict__ dst, int* __restrict__ cnt, int n) {
    int i = blockIdx.x * blockDim.x + threadIdx.x;
    if (i < n) atomicAdd(&cnt[dst[i]], 1);
}

// ---------------- scan (1024 elems/block) ----------------
__global__ void scan_block_kernel(const int* __restrict__ in, int* __restrict__ out,
                                  int* __restrict__ partials, int n) {
    __shared__ int sd[256];
    int t = threadIdx.x;
    int base = blockIdx.x * 1024 + t * 4;
    int v0 = (base + 0 < n) ? in[base + 0] : 0;
    int v1 = (base + 1 < n) ? in[base + 1] : 0;
    int v2 = (base + 2 < n) ? in[base + 2] : 0;
    int v3 = (base + 3 < n) ? in[base + 3] : 0;
    int p0 = v0, p1 = p0 + v1, p2 = p1 + v2, p3 = p2 + v3;
    sd[t] = p3;
    __syncthreads();
    for (int off = 1; off < 256; off <<= 1) {
        int x = (t >= off) ? sd[t - off] : 0;
        __syncthreads();
        sd[t] += x;
        __syncthreads();
    }
    int excl = sd[t] - p3;
    if (base + 0 < n) out[base + 0] = excl + p0;
    if (base + 1 < n) out[base + 1] = excl + p1;
    if (base + 2 < n) out[base + 2] = excl + p2;
    if (base + 3 < n) out[base + 3] = excl + p3;
    if (t == 255) partials[blockIdx.x] = sd[255];
}

__global__ void scan_partials_kernel(int* __restrict__ partials, int nb) {
    __shared__ int sd[256];
    int t = threadIdx.x;
    int v = (t < nb) ? partials[t] : 0;
    sd[t] = v;
    __syncthreads();
    for (int off = 1; off < 256; off <<= 1) {
        int x = (t >= off) ? sd[t - off] : 0;
        __syncthreads();
        sd[t] += x;
        __syncthreads();
    }
    if (t < nb) partials[t] = sd[t];
}

__global__ void scan_add_kernel(int* __restrict__ out, const int* __restrict__ partials, int n) {
    int b = blockIdx.x;
    if (b == 0) return;
    int add = partials[b - 1];
    int base = b * 1024 + threadIdx.x * 4;
    if (base + 0 < n) out[base + 0] += add;
    if (base + 1 < n) out[base + 1] += add;
    if (base + 2 < n) out[base + 2] += add;
    if (base + 3 < n) out[base + 3] += add;
}

// ---------------- CSR fill ----------------
__global__ void fill_kernel(const int* __restrict__ esrc, const int* __restrict__ edst,
                            const int* __restrict__ rp, int* __restrict__ cur,
                            int* __restrict__ ss, int n) {
    int i = blockIdx.x * blockDim.x + threadIdx.x;
    if (i < n) {
        int d = edst[i];
        int p = rp[d] + atomicAdd(&cur[d], 1);
        ss[p] = esrc[i];
    }
}

// ---------------- f32 -> fp16 streaming convert (8 elems/thread) ----------------
__global__ void to_fp16(const float* __restrict__ in, _Float16* __restrict__ outp, long n) {
    long i = ((long)blockIdx.x * blockDim.x + threadIdx.x) * 8;
    if (i >= n) return;
    f32x4 a = *reinterpret_cast<const f32x4*>(in + i);
    f32x4 b = *reinterpret_cast<const f32x4*>(in + i + 4);
    f16x8 h;
    h[0] = (_Float16)a[0]; h[1] = (_Float16)a[1]; h[2] = (_Float16)a[2]; h[3] = (_Float16)a[3];
    h[4] = (_Float16)b[0]; h[5] = (_Float16)b[1]; h[6] = (_Float16)b[2]; h[7] = (_Float16)b[3];
    *reinterpret_cast<f16x8*>(outp + i) = h;
}

// ---------------- gather + mean (one wave per dst node), fp16 source, f32 out ----------
// fp16 rows (512 B): halves the structural ~3.9x XCD-amplified miss volume of the
// random gather (round-1 finding). Accumulate f32, store f32.
// NOTE (round-7 lesson): fp16 mean output flipped an argmax (absmax 1.92) -> stays f32.
__global__ void gather_mean_fp16(const _Float16* __restrict__ Xh, const int* __restrict__ rp,
                                 const int* __restrict__ ss, float* __restrict__ mean, int ndst) {
    int wave = threadIdx.x >> 6, lane = threadIdx.x & 63;
    int d = blockIdx.x * 4 + wave;
    if (d >= ndst) return;
    int beg = rp[d], end = rp[d + 1];
    int lo4 = lane * 4;
    f32x4 a0 = (f32x4)(0.f), a1 = (f32x4)(0.f), a2 = (f32x4)(0.f), a3 = (f32x4)(0.f);
    int j = beg;
    for (; j + 8 <= end; j += 8) {
        int s0 = ss[j + 0], s1 = ss[j + 1], s2 = ss[j + 2], s3 = ss[j + 3];
        int s4 = ss[j + 4], s5 = ss[j + 5], s6 = ss[j + 6], s7 = ss[j + 7];
        f16x4 h0 = *reinterpret_cast<const f16x4*>(Xh + (size_t)s0 * DD + lo4);
        f16x4 h1 = *reinterpret_cast<const f16x4*>(Xh + (size_t)s1 * DD + lo4);
        f16x4 h2 = *reinterpret_cast<const f16x4*>(Xh + (size_t)s2 * DD + lo4);
        f16x4 h3 = *reinterpret_cast<const f16x4*>(Xh + (size_t)s3 * DD + lo4);
        f16x4 h4 = *reinterpret_cast<const f16x4*>(Xh + (size_t)s4 * DD + lo4);
        f16x4 h5 = *reinterpret_cast<const f16x4*>(Xh + (size_t)s5 * DD + lo4);
        f16x4 h6 = *reinterpret_cast<const f16x4*>(Xh + (size_t)s6 * DD + lo4);
        f16x4 h7 = *reinterpret_cast<const f16x4*>(Xh + (size_t)s7 * DD + lo4);
        a0 += __builtin_convertvector(h0, f32x4);
        a1 += __builtin_convertvector(h1, f32x4);
        a2 += __builtin_convertvector(h2, f32x4);
        a3 += __builtin_convertvector(h3, f32x4);
        a0 += __builtin_convertvector(h4, f32x4);
        a1 += __builtin_convertvector(h5, f32x4);
        a2 += __builtin_convertvector(h6, f32x4);
        a3 += __builtin_convertvector(h7, f32x4);
    }
    for (; j + 4 <= end; j += 4) {
        int s0 = ss[j + 0], s1 = ss[j + 1], s2 = ss[j + 2], s3 = ss[j + 3];
        f16x4 h0 = *reinterpret_cast<const f16x4*>(Xh + (size_t)s0 * DD + lo4);
        f16x4 h1 = *reinterpret_cast<const f16x4*>(Xh + (size_t)s1 * DD + lo4);
        f16x4 h2 = *reinterpret_cast<const f16x4*>(Xh + (size_t)s2 * DD + lo4);
        f16x4 h3 = *reinterpret_cast<const f16x4*>(Xh + (size_t)s3 * DD + lo4);
        a0 += __builtin_convertvector(h0, f32x4);
        a1 += __builtin_convertvector(h1, f32x4);
        a2 += __builtin_convertvector(h2, f32x4);
        a3 += __builtin_convertvector(h3, f32x4);
    }
    for (; j < end; ++j) {
        int s = ss[j];
        f16x4 h0 = *reinterpret_cast<const f16x4*>(Xh + (size_t)s * DD + lo4);
        a0 += __builtin_convertvector(h0, f32x4);
    }
    f32x4 s = (a0 + a1) + (a2 + a3);
    int dg = end - beg;
    float inv = 1.0f / (float)(dg > 0 ? dg : 1);
    s *= inv;
    *reinterpret_cast<f32x4*>(mean + (size_t)d * DD + lo4) = s;
}

// ---------------- build 2-level fp16 split weight image (layers, pre-swizzled) -------------
__global__ void build_wimg(const float* __restrict__ Wa0, const float* __restrict__ Wb0,
                           const float* __restrict__ Wa1, const float* __restrict__ Wb1,
                           u16* __restrict__ img) {
    int blk = blockIdx.x;           // 0..63
    int layer = blk >> 5;
    int ntile = (blk >> 4) & 1;
    int chunk = blk & 15;
    const float* Wa = layer ? Wa1 : Wa0;
    const float* Wb = layer ? Wb1 : Wb0;
    int t = threadIdx.x;
    int row = t >> 1, half = t & 1;
    int n = ntile * 128 + row;
    int kg = chunk * 32 + half * 16;
    const float* W = (kg < 256) ? Wa : Wb;
    int kk = kg & 255;
    float x[16];
    loadA_f32(W + (size_t)n * 256 + kk, x);
    int rs = (row >> 1) & 3;
    int q0 = (half * 2 + 0) ^ rs;
    int q1 = (half * 2 + 1) ^ rs;
    writeA_f32(x, img + (size_t)blk * IMG_U16 + row * 32, q0, q1);
}

// ---------------- build head weight image: rows = [Wp(7) | Wpp(280) | zeros(97)] -----------
__global__ void build_wimg_head(const float* __restrict__ Wp, const float* __restrict__ Wpp,
                                u16* __restrict__ img) {
    int blk = blockIdx.x;           // 0..47 = ntile*16 + chunk
    int ntile = blk >> 4;
    int chunk = blk & 15;
    int t = threadIdx.x;
    int row = t >> 1, half = t & 1;
    int r = ntile * 128 + row;      // output col 0..383
    int kg = chunk * 32 + half * 16;
    float x[16];
    const float* src = nullptr;
    if (r < CC)                src = Wp  + (size_t)r * 512 + kg;
    else if (r < CC + CC * KK) src = Wpp + (size_t)(r - CC) * 512 + kg;
    if (src) loadA_f32(src, x);
    else {
#pragma unroll
        for (int j = 0; j < 16; ++j) x[j] = 0.f;
    }
    int rs = (row >> 1) & 3;
    int q0 = (half * 2 + 0) ^ rs;
    int q1 = (half * 2 + 1) ^ rs;
    writeA_f32(x, img + (size_t)blk * IMG_U16 + row * 32, q0, q1);
}

// ---------------- split MFMA GEMM, 2-phase pipelined (f32 A, 2-level, 3 MFMA) ----------
// out = act([X0 | X1] @ Wimg^T + b). Numerics identical to the round-6 kernel.
// Pipeline: B double-buffered (global_load_lds issued 1 chunk ahead); A global loads
// issued 1 chunk ahead into regs, ds_written after barrier1 (async-STAGE split).
// LDS 48KB -> 3 blocks/CU.
__global__ __launch_bounds__(256, 3) void gemm_f16(const float* __restrict__ X0,
                                                   const float* __restrict__ X1,
                                                   const u16* __restrict__ imgL,
                                                   const float* __restrict__ bias,
                                                   float* __restrict__ out,
                                                   _Float16* __restrict__ outh,
                                                   int M, int ldo, int dorelu) {
    __shared__ __align__(16) u16 Asl[2 * LVL2_U16];
    __shared__ __align__(16) u16 Bsl[2][2 * LVL2_U16];
    int t = threadIdx.x;
    int wave = t >> 6, lane = t & 63;
    int m0 = blockIdx.x * 128;
    int ntile = blockIdx.y;
    int wy = wave >> 1, wx = wave & 1;     // wave position: m-half, n-half

    f32x4 acc[4][4];
#pragma unroll
    for (int i = 0; i < 4; ++i)
#pragma unroll
        for (int j = 0; j < 4; ++j) acc[i][j] = (f32x4)(0.f);

    // A staging mapping: 256 thr -> 128 rows x 2 k-halves (16 f32 each)
    int arow_l = t >> 1;
    int akh = t & 1;
    int arow = m0 + arow_l; if (arow >= M) arow = M - 1;
    int rsw = (arow_l >> 1) & 3;
    int q0w = (akh * 2 + 0) ^ rsw;
    int q1w = (akh * 2 + 1) ^ rsw;

    // fragment positions: A/B operand elem j -> k = (lane>>4)*8 + j  => quad q = lane>>4
    int fr = lane & 15;
    int q  = lane >> 4;
    int frm = wy * 64 + fr;
    int frn = wx * 64 + fr;

    const u16* imgT = imgL + (size_t)ntile * 16 * IMG_U16;

    float xa[16];

    auto issueB = [&](int cc, int buf) {
        const char* srcB = (const char*)(imgT + (size_t)cc * IMG_U16);
        char* dstB = (char*)Bsl[buf];
#pragma unroll
        for (int i = 0; i < 4; ++i) {
            int seg = wave * 4 + i;
            async16(srcB + seg * 1024 + lane * 16, dstB + seg * 1024 + lane * 16);
        }
    };
    auto loadA = [&](int cc) {
        const float* Xs = (cc < 8) ? X0 : X1;
        loadA_f32(Xs + (size_t)arow * 256 + (cc & 7) * 32 + akh * 16, xa);
    };
    auto writeA = [&]() {
        writeA_f32(xa, Asl + arow_l * 32, q0w, q1w);
    };

    // prologue: chunk 0
    issueB(0, 0);
    loadA(0);
    writeA();
    __syncthreads();

    for (int c = 0; c < 16; ++c) {
        int nc = c + 1;
        if (nc < 16) {              // issue next-chunk B (other buffer) + A (regs) early
            issueB(nc, nc & 1);
            loadA(nc);
        }
        // ---- compute chunk c from Bsl[c&1] + Asl
        const u16* B = Bsl[c & 1];
        f16x8 bf[4][2];
#pragma unroll
        for (int ns = 0; ns < 4; ++ns) {
            int r = frn + ns * 16;
            int off = r * 32 + ((q ^ ((r >> 1) & 3))) * 8;
            bf[ns][0] = *reinterpret_cast<const f16x8*>(B + off);
            bf[ns][1] = *reinterpret_cast<const f16x8*>(B + LVL2_U16 + off);
        }
#pragma unroll
        for (int ms = 0; ms < 4; ++ms) {
            int r = frm + ms * 16;
            int off = r * 32 + ((q ^ ((r >> 1) & 3))) * 8;
            f16x8 af0 = *reinterpret_cast<const f16x8*>(Asl + off);
            f16x8 af1 = *reinterpret_cast<const f16x8*>(Asl + LVL2_U16 + off);
#pragma unroll
            for (int ns = 0; ns < 4; ++ns) {
                f32x4 a = acc[ms][ns];
                a = __builtin_amdgcn_mfma_f32_16x16x32_f16(af0, bf[ns][0], a, 0, 0, 0);
                a = __builtin_amdgcn_mfma_f32_16x16x32_f16(af0, bf[ns][1], a, 0, 0, 0);
                a = __builtin_amdgcn_mfma_f32_16x16x32_f16(af1, bf[ns][0], a, 0, 0, 0);
                acc[ms][ns] = a;
            }
        }
        __syncthreads();            // drains B(nc) async + A(nc) loads (overlapped w/ compute)
        if (nc < 16) {
            writeA();               // ds_write next A from regs
            __syncthreads();
        }
    }
    // ---- epilogue: +bias, act, store f32 (C/D: col=lane&15, row=(lane>>4)*4+reg)
#pragma unroll
    for (int ms = 0; ms < 4; ++ms) {
        int rbase = m0 + wy * 64 + ms * 16 + (lane >> 4) * 4;
#pragma unroll
        for (int ns = 0; ns < 4; ++ns) {
            int col = ntile * 128 + wx * 64 + ns * 16 + (lane & 15);
            if (col >= ldo) continue;
            float bcol = bias ? bias[col] : 0.f;
#pragma unroll
            for (int r = 0; r < 4; ++r) {
                int row = rbase + r;
                if (row < M) {
                    float v = acc[ms][ns][r] + bcol;
                    if (dorelu) v = fmaxf(v, 0.f);
                    out[(size_t)row * ldo + col] = v;
                    if (outh) outh[(size_t)row * DD + col] = (_Float16)v;
                }
            }
        }
    }
}

// ---------------- head select: argmax over 7 score cols -> copy chosen 40 ----------------
__global__ void select_kernel(const float* __restrict__ all, float* __restrict__ out) {
    int wave = threadIdx.x >> 6, lane = threadIdx.x & 63;
    int n = blockIdx.x * 4 + wave;
    if (n >= NN2) return;
    const float* row = all + (size_t)n * NHEAD;
    float best = row[0]; int bc = 0;
#pragma unroll
    for (int c = 1; c < CC; ++c) {
        float s = row[c];
        if (s > best) { best = s; bc = c; }  // strict > : first-index tie-break (np.argmax)
    }
    if (lane < KK) out[(size_t)n * KK + lane] = row[CC + bc * KK + lane];
}

extern "C" void kernel_launch(void* const* d_in, const int* in_sizes, int n_in,
                              void* d_out, int out_size, void* d_ws, size_t ws_size,
                              hipStream_t stream) {
    const float* inputs  = (const float*)d_in[0];
    const float* Wself0  = (const float*)d_in[1];
    const float* Wneigh0 = (const float*)d_in[2];
    const float* b0      = (const float*)d_in[3];
    const float* Wself1  = (const float*)d_in[4];
    const float* Wneigh1 = (const float*)d_in[5];
    const float* b1      = (const float*)d_in[6];
    const float* Wp      = (const float*)d_in[7];
    const float* Wpp     = (const float*)d_in[8];
    const int* es0 = (const int*)d_in[9];
    const int* ed0 = (const int*)d_in[10];
    const int* es1 = (const int*)d_in[11];
    const int* ed1 = (const int*)d_in[12];

    char* ws = (char*)d_ws;
    size_t off = 0;
    auto alloc = [&](size_t bytes) -> void* {
        void* p = (void*)(ws + off);
        off += (bytes + 255) & ~(size_t)255;
        return p;
    };
    // zero-initialized region (one memset)
    int* cnt0 = (int*)alloc((size_t)NN1 * 4);
    int* cnt1 = (int*)alloc((size_t)NN2 * 4);
    int* cur0 = (int*)alloc((size_t)NN1 * 4);
    int* cur1 = (int*)alloc((size_t)NN2 * 4);
    int* rp0  = (int*)alloc((size_t)(NN1 + 1) * 4);
    int* rp1  = (int*)alloc((size_t)(NN2 + 1) * 4);
    int* part0 = (int*)alloc(1024);
    int* part1 = (int*)alloc(1024);
    size_t zero_bytes = off;
    // uninitialized scratch
    int*   ss0   = (int*)alloc((size_t)EE0 * 4);
    int*   ss1   = (int*)alloc((size_t)EE1 * 4);
    u16*   wimg  = (u16*)alloc((size_t)(64 + 48) * IMG_U16 * 2); // layer(64) + head(48) images
    u16*   wimgH = wimg + (size_t)64 * IMG_U16;
    // xh (fp16 inputs, 102.4MB) aliases h1 (f32, 102.4MB): xh is dead before
    // gemm0 writes h1 (serial stream: to_fp16 -> gather0 reads xh -> gemm0 writes h1).
    _Float16* xh = (_Float16*)alloc((size_t)NN0 * DD * 2);
    float*    h1 = (float*)xh;
    _Float16* h1h  = (_Float16*)alloc((size_t)NN1 * DD * 2);  // fp16 shadow of h1 for gather1
    float* mean0 = (float*)alloc((size_t)NN1 * DD * 4);
    float* mean1 = mean0;                      // mean0 dead after gemm0; reuse
    float* h2    = mean0 + (size_t)NN2 * DD;   // second half of the same region
    float* allout = (float*)alloc((size_t)NN2 * NHEAD * 4);   // 57.6 MB head output

    hipMemsetAsync(d_ws, 0, zero_bytes, stream);

    // CSR build, layer 0 and 1
    hist_kernel<<<(EE0 + 255) / 256, 256, 0, stream>>>(ed0, cnt0, EE0);
    hist_kernel<<<(EE1 + 255) / 256, 256, 0, stream>>>(ed1, cnt1, EE1);
    int nb0 = (NN1 + 1023) / 1024, nb1 = (NN2 + 1023) / 1024;
    scan_block_kernel<<<nb0, 256, 0, stream>>>(cnt0, rp0 + 1, part0, NN1);
    scan_partials_kernel<<<1, 256, 0, stream>>>(part0, nb0);
    scan_add_kernel<<<nb0, 256, 0, stream>>>(rp0 + 1, part0, NN1);
    scan_block_kernel<<<nb1, 256, 0, stream>>>(cnt1, rp1 + 1, part1, NN2);
    scan_partials_kernel<<<1, 256, 0, stream>>>(part1, nb1);
    scan_add_kernel<<<nb1, 256, 0, stream>>>(rp1 + 1, part1, NN2);
    fill_kernel<<<(EE0 + 255) / 256, 256, 0, stream>>>(es0, ed0, rp0, cur0, ss0, EE0);
    fill_kernel<<<(EE1 + 255) / 256, 256, 0, stream>>>(es1, ed1, rp1, cur1, ss1, EE1);

    // split weights into pre-swizzled fp16 images (layers + head)
    build_wimg<<<64, 256, 0, stream>>>(Wself0, Wneigh0, Wself1, Wneigh1, wimg);
    build_wimg_head<<<48, 256, 0, stream>>>(Wp, Wpp, wimgH);

    // fp16 copy of inputs for the gather (halves random-gather miss bytes)
    long nx = (long)NN0 * DD;
    to_fp16<<<(int)(nx / 8 / 256), 256, 0, stream>>>(inputs, xh, nx);

    // layer 0: mean aggregate (fp16 gather, f32 out) + pipelined split-MFMA GEMM
    gather_mean_fp16<<<(NN1 + 3) / 4, 256, 0, stream>>>(xh, rp0, ss0, mean0, NN1);
    dim3 g0((NN1 + 127) / 128, 2);
    gemm_f16<<<g0, 256, 0, stream>>>(inputs, mean0, wimg, b0, h1, h1h, NN1, DD, 1);

    // layer 1 (gather reads fp16 shadow)
    gather_mean_fp16<<<(NN2 + 3) / 4, 256, 0, stream>>>(h1h, rp1, ss1, mean1, NN2);
    dim3 g1((NN2 + 127) / 128, 2);
    gemm_f16<<<g1, 256, 0, stream>>>(h1, mean1, wimg + (size_t)32 * IMG_U16, b1, h2, nullptr, NN2, DD, 1);

    // head as GEMM: all 287 outputs (7 scores + 280 projections) via MFMA, then select
    dim3 gh((NN2 + 127) / 128, 3);
    gemm_f16<<<gh, 256, 0, stream>>>(h2, h1, wimgH, nullptr, allout, nullptr, NN2, NHEAD, 0);
    select_kernel<<<(NN2 + 3) / 4, 256, 0, stream>>>(allout, (float*)d_out);
}

// Round 9
// 1064.686 us; speedup vs baseline: 1.0179x; 1.0179x over previous
//
#include <hip/hip_runtime.h>
#include <stdint.h>

typedef unsigned short u16;
typedef unsigned int   u32;
typedef float f32x4  __attribute__((ext_vector_type(4)));
typedef _Float16 f16x4 __attribute__((ext_vector_type(4)));
typedef _Float16 f16x8 __attribute__((ext_vector_type(8)));

#define NN0 200000
#define NN1 100000
#define NN2 50000
#define EE0 1600000
#define EE1 800000
#define DD  256
#define CC  7
#define KK  40
#define NHEAD 288               // 7 scores + 280 proj + 1 pad col

// fp16 2-level split image geometry (weights AND activations):
// per (tile, chunk): 2 levels x 128 rows x 32 fp16 = 16384 B, XOR-swizzled
// swizzle: 16-B quad q (k>>3) stored at q ^ ((row>>1)&3)  -> conflict-free b128 r/w
// A-images: [mblock][chunk 8][lvl 2][row 128][32], mblock stride 8*IMG_U16
#define LVL2_U16 4096           // u16 per level (128 rows x 32)
#define IMG_U16  8192           // u16 per chunk image (2 levels)
#define AIMG_STRIDE (8 * IMG_U16)

// ---------------- split f32 -> 2 fp16 (residual) ----------------
static __device__ __forceinline__ void split2(float x, _Float16& t0, _Float16& t1) {
    t0 = (_Float16)x;
    t1 = (_Float16)(x - (float)t0);
}

static __device__ __forceinline__ f16x8 pack8(const _Float16* h) {
    f16x8 v;
#pragma unroll
    for (int i = 0; i < 8; ++i) v[i] = h[i];
    return v;
}

static __device__ __forceinline__ void async16(const void* g, void* l) {
    __builtin_amdgcn_global_load_lds(
        (const __attribute__((address_space(1))) void*)g,
        (__attribute__((address_space(3))) void*)l, 16, 0, 0);
}

static __device__ __forceinline__ void loadA_f32(const float* p, float* xa) {
#pragma unroll
    for (int j = 0; j < 16; j += 4) {
        float4 v = *reinterpret_cast<const float4*>(p + j);
        xa[j] = v.x; xa[j + 1] = v.y; xa[j + 2] = v.z; xa[j + 3] = v.w;
    }
}

static __device__ __forceinline__ void writeA_f32(const float* xa, u16* d, int q0, int q1) {
    _Float16 h0[16], h1v[16];
#pragma unroll
    for (int j = 0; j < 16; ++j) split2(xa[j], h0[j], h1v[j]);
    *reinterpret_cast<f16x8*>(d + q0 * 8)            = pack8(h0);
    *reinterpret_cast<f16x8*>(d + q1 * 8)            = pack8(h0 + 8);
    *reinterpret_cast<f16x8*>(d + LVL2_U16 + q0 * 8) = pack8(h1v);
    *reinterpret_cast<f16x8*>(d + LVL2_U16 + q1 * 8) = pack8(h1v + 8);
}

// ---------------- histogram ----------------
__global__ void hist_kernel(const int* __restrict__ dst, int* __restrict__ cnt, int n) {
    int i = blockIdx.x * blockDim.x + threadIdx.x;
    if (i < n) atomicAdd(&cnt[dst[i]], 1);
}

// ---------------- scan (1024 elems/block) ----------------
__global__ void scan_block_kernel(const int* __restrict__ in, int* __restrict__ out,
                                  int* __restrict__ partials, int n) {
    __shared__ int sd[256];
    int t = threadIdx.x;
    int base = blockIdx.x * 1024 + t * 4;
    int v0 = (base + 0 < n) ? in[base + 0] : 0;
    int v1 = (base + 1 < n) ? in[base + 1] : 0;
    int v2 = (base + 2 < n) ? in[base + 2] : 0;
    int v3 = (base + 3 < n) ? in[base + 3] : 0;
    int p0 = v0, p1 = p0 + v1, p2 = p1 + v2, p3 = p2 + v3;
    sd[t] = p3;
    __syncthreads();
    for (int off = 1; off < 256; off <<= 1) {
        int x = (t >= off) ? sd[t - off] : 0;
        __syncthreads();
        sd[t] += x;
        __syncthreads();
    }
    int excl = sd[t] - p3;
    if (base + 0 < n) out[base + 0] = excl + p0;
    if (base + 1 < n) out[base + 1] = excl + p1;
    if (base + 2 < n) out[base + 2] = excl + p2;
    if (base + 3 < n) out[base + 3] = excl + p3;
    if (t == 255) partials[blockIdx.x] = sd[255];
}

__global__ void scan_partials_kernel(int* __restrict__ partials, int nb) {
    __shared__ int sd[256];
    int t = threadIdx.x;
    int v = (t < nb) ? partials[t] : 0;
    sd[t] = v;
    __syncthreads();
    for (int off = 1; off < 256; off <<= 1) {
        int x = (t >= off) ? sd[t - off] : 0;
        __syncthreads();
        sd[t] += x;
        __syncthreads();
    }
    if (t < nb) partials[t] = sd[t];
}

__global__ void scan_add_kernel(int* __restrict__ out, const int* __restrict__ partials, int n) {
    int b = blockIdx.x;
    if (b == 0) return;
    int add = partials[b - 1];
    int base = b * 1024 + threadIdx.x * 4;
    if (base + 0 < n) out[base + 0] += add;
    if (base + 1 < n) out[base + 1] += add;
    if (base + 2 < n) out[base + 2] += add;
    if (base + 3 < n) out[base + 3] += add;
}

// ---------------- CSR fill ----------------
__global__ void fill_kernel(const int* __restrict__ esrc, const int* __restrict__ edst,
                            const int* __restrict__ rp, int* __restrict__ cur,
                            int* __restrict__ ss, int n) {
    int i = blockIdx.x * blockDim.x + threadIdx.x;
    if (i < n) {
        int d = edst[i];
        int p = rp[d] + atomicAdd(&cur[d], 1);
        ss[p] = esrc[i];
    }
}

// ---------------- f32 -> fp16 + tiled split image of rows < NN1 ----------------
// xh (row-linear fp16) feeds the gather; imgX (tiled t0/t1 planes) feeds gemm0's A.
__global__ void to_fp16_split(const float* __restrict__ in, _Float16* __restrict__ xh,
                              u16* __restrict__ imgX, long n) {
    long i = ((long)blockIdx.x * blockDim.x + threadIdx.x) * 8;
    if (i >= n) return;
    f32x4 a = *reinterpret_cast<const f32x4*>(in + i);
    f32x4 b = *reinterpret_cast<const f32x4*>(in + i + 4);
    float x[8] = {a[0], a[1], a[2], a[3], b[0], b[1], b[2], b[3]};
    _Float16 t0[8], t1[8];
#pragma unroll
    for (int j = 0; j < 8; ++j) split2(x[j], t0[j], t1[j]);
    *reinterpret_cast<f16x8*>(xh + i) = pack8(t0);
    int row = (int)(i >> 8);
    if (row < NN1) {
        int k = (int)(i & 255);
        int lrow = row & 127, ch = k >> 5;
        int qs = ((k & 31) >> 3) ^ ((lrow >> 1) & 3);
        u16* p = imgX + (size_t)(row >> 7) * AIMG_STRIDE + (size_t)ch * IMG_U16
               + lrow * 32 + qs * 8;
        *reinterpret_cast<f16x8*>(p)            = pack8(t0);
        *reinterpret_cast<f16x8*>(p + LVL2_U16) = pack8(t1);
    }
}

// ---------------- gather + mean (one wave per dst node), fp16 source, tiled split out ----
// fp16 rows (512 B): halves the structural ~3.9x XCD-amplified miss volume of the
// random gather (round-1 finding). Accumulate f32, write the mean's split image
// directly (same bytes as an f32 store; gemm A-stage becomes a pure DMA copy).
__global__ void gather_mean_fp16(const _Float16* __restrict__ Xh, const int* __restrict__ rp,
                                 const int* __restrict__ ss, u16* __restrict__ imgM, int ndst) {
    int wave = threadIdx.x >> 6, lane = threadIdx.x & 63;
    int d = blockIdx.x * 4 + wave;
    if (d >= ndst) return;
    int beg = rp[d], end = rp[d + 1];
    int lo4 = lane * 4;
    f32x4 a0 = (f32x4)(0.f), a1 = (f32x4)(0.f), a2 = (f32x4)(0.f), a3 = (f32x4)(0.f);
    int j = beg;
    for (; j + 8 <= end; j += 8) {
        int s0 = ss[j + 0], s1 = ss[j + 1], s2 = ss[j + 2], s3 = ss[j + 3];
        int s4 = ss[j + 4], s5 = ss[j + 5], s6 = ss[j + 6], s7 = ss[j + 7];
        f16x4 h0 = *reinterpret_cast<const f16x4*>(Xh + (size_t)s0 * DD + lo4);
        f16x4 h1 = *reinterpret_cast<const f16x4*>(Xh + (size_t)s1 * DD + lo4);
        f16x4 h2 = *reinterpret_cast<const f16x4*>(Xh + (size_t)s2 * DD + lo4);
        f16x4 h3 = *reinterpret_cast<const f16x4*>(Xh + (size_t)s3 * DD + lo4);
        f16x4 h4 = *reinterpret_cast<const f16x4*>(Xh + (size_t)s4 * DD + lo4);
        f16x4 h5 = *reinterpret_cast<const f16x4*>(Xh + (size_t)s5 * DD + lo4);
        f16x4 h6 = *reinterpret_cast<const f16x4*>(Xh + (size_t)s6 * DD + lo4);
        f16x4 h7 = *reinterpret_cast<const f16x4*>(Xh + (size_t)s7 * DD + lo4);
        a0 += __builtin_convertvector(h0, f32x4);
        a1 += __builtin_convertvector(h1, f32x4);
        a2 += __builtin_convertvector(h2, f32x4);
        a3 += __builtin_convertvector(h3, f32x4);
        a0 += __builtin_convertvector(h4, f32x4);
        a1 += __builtin_convertvector(h5, f32x4);
        a2 += __builtin_convertvector(h6, f32x4);
        a3 += __builtin_convertvector(h7, f32x4);
    }
    for (; j + 4 <= end; j += 4) {
        int s0 = ss[j + 0], s1 = ss[j + 1], s2 = ss[j + 2], s3 = ss[j + 3];
        f16x4 h0 = *reinterpret_cast<const f16x4*>(Xh + (size_t)s0 * DD + lo4);
        f16x4 h1 = *reinterpret_cast<const f16x4*>(Xh + (size_t)s1 * DD + lo4);
        f16x4 h2 = *reinterpret_cast<const f16x4*>(Xh + (size_t)s2 * DD + lo4);
        f16x4 h3 = *reinterpret_cast<const f16x4*>(Xh + (size_t)s3 * DD + lo4);
        a0 += __builtin_convertvector(h0, f32x4);
        a1 += __builtin_convertvector(h1, f32x4);
        a2 += __builtin_convertvector(h2, f32x4);
        a3 += __builtin_convertvector(h3, f32x4);
    }
    for (; j < end; ++j) {
        int s = ss[j];
        f16x4 h0 = *reinterpret_cast<const f16x4*>(Xh + (size_t)s * DD + lo4);
        a0 += __builtin_convertvector(h0, f32x4);
    }
    f32x4 s = (a0 + a1) + (a2 + a3);
    int dg = end - beg;
    float inv = 1.0f / (float)(dg > 0 ? dg : 1);
    s *= inv;
    f16x4 t0v, t1v;
#pragma unroll
    for (int jj = 0; jj < 4; ++jj) { _Float16 ta, tb; split2(s[jj], ta, tb); t0v[jj] = ta; t1v[jj] = tb; }
    int lrow = d & 127, ch = lane >> 3;
    int qs = ((lane >> 1) & 3) ^ ((lrow >> 1) & 3);
    u16* p = imgM + (size_t)(d >> 7) * AIMG_STRIDE + (size_t)ch * IMG_U16
           + lrow * 32 + qs * 8 + (lane & 1) * 4;
    *reinterpret_cast<f16x4*>(p)            = t0v;
    *reinterpret_cast<f16x4*>(p + LVL2_U16) = t1v;
}

// ---------------- build 2-level fp16 split weight image (layers, pre-swizzled) -------------
__global__ void build_wimg(const float* __restrict__ Wa0, const float* __restrict__ Wb0,
                           const float* __restrict__ Wa1, const float* __restrict__ Wb1,
                           u16* __restrict__ img) {
    int blk = blockIdx.x;           // 0..63
    int layer = blk >> 5;
    int ntile = (blk >> 4) & 1;
    int chunk = blk & 15;
    const float* Wa = layer ? Wa1 : Wa0;
    const float* Wb = layer ? Wb1 : Wb0;
    int t = threadIdx.x;
    int row = t >> 1, half = t & 1;
    int n = ntile * 128 + row;
    int kg = chunk * 32 + half * 16;
    const float* W = (kg < 256) ? Wa : Wb;
    int kk = kg & 255;
    float x[16];
    loadA_f32(W + (size_t)n * 256 + kk, x);
    int rs = (row >> 1) & 3;
    int q0 = (half * 2 + 0) ^ rs;
    int q1 = (half * 2 + 1) ^ rs;
    writeA_f32(x, img + (size_t)blk * IMG_U16 + row * 32, q0, q1);
}

// ---------------- build head weight image: rows = [Wp(7) | Wpp(280) | zeros(97)] -----------
__global__ void build_wimg_head(const float* __restrict__ Wp, const float* __restrict__ Wpp,
                                u16* __restrict__ img) {
    int blk = blockIdx.x;           // 0..47 = ntile*16 + chunk
    int ntile = blk >> 4;
    int chunk = blk & 15;
    int t = threadIdx.x;
    int row = t >> 1, half = t & 1;
    int r = ntile * 128 + row;      // output col 0..383
    int kg = chunk * 32 + half * 16;
    float x[16];
    const float* src = nullptr;
    if (r < CC)                src = Wp  + (size_t)r * 512 + kg;
    else if (r < CC + CC * KK) src = Wpp + (size_t)(r - CC) * 512 + kg;
    if (src) loadA_f32(src, x);
    else {
#pragma unroll
        for (int j = 0; j < 16; ++j) x[j] = 0.f;
    }
    int rs = (row >> 1) & 3;
    int q0 = (half * 2 + 0) ^ rs;
    int q1 = (half * 2 + 1) ^ rs;
    writeA_f32(x, img + (size_t)blk * IMG_U16 + row * 32, q0, q1);
}

// ---------------- split MFMA GEMM, image-fed A and B (pure-DMA staging) ----------------
// out = act([A0 | A1] @ Wimg^T + b). A0/A1 = pre-split tiled images (chunks 0..7 each).
// No in-kernel split / ds_write: both operands staged with global_load_lds (m97 structure).
// Outputs: optional f32 (stride ldo, cols < ldo), optional split image, optional fp16 linear.
__global__ __launch_bounds__(256, 4) void gemm_img(const u16* __restrict__ imgA0,
                                                   const u16* __restrict__ imgA1,
                                                   const u16* __restrict__ imgB,
                                                   const float* __restrict__ bias,
                                                   float* __restrict__ out,
                                                   u16* __restrict__ imgOut,
                                                   _Float16* __restrict__ outh,
                                                   int M, int ldo, int dorelu) {
    __shared__ __align__(16) u16 Asl[IMG_U16];
    __shared__ __align__(16) u16 Bsl[IMG_U16];
    int t = threadIdx.x;
    int wave = t >> 6, lane = t & 63;
    int m0 = blockIdx.x * 128;
    int ntile = blockIdx.y;
    int wy = wave >> 1, wx = wave & 1;     // wave position: m-half, n-half

    f32x4 acc[4][4];
#pragma unroll
    for (int i = 0; i < 4; ++i)
#pragma unroll
        for (int j = 0; j < 4; ++j) acc[i][j] = (f32x4)(0.f);

    // fragment positions: A/B operand elem j -> k = (lane>>4)*8 + j  => quad q = lane>>4
    int fr = lane & 15;
    int q  = lane >> 4;
    int frm = wy * 64 + fr;
    int frn = wx * 64 + fr;

    const u16* imgBT = imgB + (size_t)ntile * 16 * IMG_U16;
    size_t mboff = (size_t)blockIdx.x * AIMG_STRIDE;

    for (int c = 0; c < 16; ++c) {
        // ---- stage A and B: linear 16 KB async copies each (4 segs of 1KB per wave)
        const char* sB = (const char*)(imgBT + (size_t)c * IMG_U16);
        const char* sA = (const char*)((c < 8) ? imgA0 + mboff + (size_t)c * IMG_U16
                                               : imgA1 + mboff + (size_t)(c - 8) * IMG_U16);
#pragma unroll
        for (int i = 0; i < 4; ++i) {
            int off = (wave * 4 + i) * 1024 + lane * 16;
            async16(sB + off, (char*)Bsl + off);
            async16(sA + off, (char*)Asl + off);
        }
        __syncthreads();
        // ---- fragments + MFMA (3 per subtile: t0w0, t0w1, t1w0)
        f16x8 bf[4][2];
#pragma unroll
        for (int ns = 0; ns < 4; ++ns) {
            int r = frn + ns * 16;
            int off = r * 32 + ((q ^ ((r >> 1) & 3))) * 8;
            bf[ns][0] = *reinterpret_cast<const f16x8*>(Bsl + off);
            bf[ns][1] = *reinterpret_cast<const f16x8*>(Bsl + LVL2_U16 + off);
        }
#pragma unroll
        for (int ms = 0; ms < 4; ++ms) {
            int r = frm + ms * 16;
            int off = r * 32 + ((q ^ ((r >> 1) & 3))) * 8;
            f16x8 af0 = *reinterpret_cast<const f16x8*>(Asl + off);
            f16x8 af1 = *reinterpret_cast<const f16x8*>(Asl + LVL2_U16 + off);
#pragma unroll
            for (int ns = 0; ns < 4; ++ns) {
                f32x4 a = acc[ms][ns];
                a = __builtin_amdgcn_mfma_f32_16x16x32_f16(af0, bf[ns][0], a, 0, 0, 0);
                a = __builtin_amdgcn_mfma_f32_16x16x32_f16(af0, bf[ns][1], a, 0, 0, 0);
                a = __builtin_amdgcn_mfma_f32_16x16x32_f16(af1, bf[ns][0], a, 0, 0, 0);
                acc[ms][ns] = a;
            }
        }
        __syncthreads();
    }
    // ---- epilogue: +bias, act, store (C/D: col=lane&15, row=(lane>>4)*4+reg)
#pragma unroll
    for (int ms = 0; ms < 4; ++ms) {
        int rbase = m0 + wy * 64 + ms * 16 + (lane >> 4) * 4;
#pragma unroll
        for (int ns = 0; ns < 4; ++ns) {
            int col = ntile * 128 + wx * 64 + ns * 16 + (lane & 15);
            float bcol = bias ? bias[col] : 0.f;
#pragma unroll
            for (int r = 0; r < 4; ++r) {
                int row = rbase + r;
                if (row >= M) continue;
                float v = acc[ms][ns][r] + bcol;
                if (dorelu) v = fmaxf(v, 0.f);
                if (out && col < ldo) out[(size_t)row * ldo + col] = v;
                if (outh) outh[(size_t)row * DD + col] = (_Float16)v;
                if (imgOut) {
                    _Float16 t0, t1;
                    split2(v, t0, t1);
                    int lrow = row & 127, ch = col >> 5, kk = col & 31;
                    int qs = (kk >> 3) ^ ((lrow >> 1) & 3);
                    u16* p = imgOut + (size_t)(row >> 7) * AIMG_STRIDE + (size_t)ch * IMG_U16
                           + lrow * 32 + qs * 8 + (kk & 7);
                    p[0]        = __builtin_bit_cast(u16, t0);
                    p[LVL2_U16] = __builtin_bit_cast(u16, t1);
                }
            }
        }
    }
}

// ---------------- head select: argmax over 7 score cols -> copy chosen 40 ----------------
__global__ void select_kernel(const float* __restrict__ all, float* __restrict__ out) {
    int wave = threadIdx.x >> 6, lane = threadIdx.x & 63;
    int n = blockIdx.x * 4 + wave;
    if (n >= NN2) return;
    const float* row = all + (size_t)n * NHEAD;
    float best = row[0]; int bc = 0;
#pragma unroll
    for (int c = 1; c < CC; ++c) {
        float s = row[c];
        if (s > best) { best = s; bc = c; }  // strict > : first-index tie-break (np.argmax)
    }
    if (lane < KK) out[(size_t)n * KK + lane] = row[CC + bc * KK + lane];
}

extern "C" void kernel_launch(void* const* d_in, const int* in_sizes, int n_in,
                              void* d_out, int out_size, void* d_ws, size_t ws_size,
                              hipStream_t stream) {
    const float* inputs  = (const float*)d_in[0];
    const float* Wself0  = (const float*)d_in[1];
    const float* Wneigh0 = (const float*)d_in[2];
    const float* b0      = (const float*)d_in[3];
    const float* Wself1  = (const float*)d_in[4];
    const float* Wneigh1 = (const float*)d_in[5];
    const float* b1      = (const float*)d_in[6];
    const float* Wp      = (const float*)d_in[7];
    const float* Wpp     = (const float*)d_in[8];
    const int* es0 = (const int*)d_in[9];
    const int* ed0 = (const int*)d_in[10];
    const int* es1 = (const int*)d_in[11];
    const int* ed1 = (const int*)d_in[12];

    char* ws = (char*)d_ws;
    size_t off = 0;
    auto alloc = [&](size_t bytes) -> void* {
        void* p = (void*)(ws + off);
        off += (bytes + 255) & ~(size_t)255;
        return p;
    };
    // zero-initialized region (one memset)
    int* cnt0 = (int*)alloc((size_t)NN1 * 4);
    int* cnt1 = (int*)alloc((size_t)NN2 * 4);
    int* cur0 = (int*)alloc((size_t)NN1 * 4);
    int* cur1 = (int*)alloc((size_t)NN2 * 4);
    int* rp0  = (int*)alloc((size_t)(NN1 + 1) * 4);
    int* rp1  = (int*)alloc((size_t)(NN2 + 1) * 4);
    int* part0 = (int*)alloc(1024);
    int* part1 = (int*)alloc(1024);
    size_t zero_bytes = off;
    // uninitialized scratch
    int*   ss0   = (int*)alloc((size_t)EE0 * 4);
    int*   ss1   = (int*)alloc((size_t)EE1 * 4);
    u16*   wimg  = (u16*)alloc((size_t)(64 + 48) * IMG_U16 * 2); // layer(64) + head(48) B-images
    u16*   wimgH = wimg + (size_t)64 * IMG_U16;
    const int MB1 = (NN1 + 127) / 128;   // 782 mblocks
    const int MB2 = (NN2 + 127) / 128;   // 391 mblocks
    u16* imgX0   = (u16*)alloc((size_t)MB1 * AIMG_STRIDE * 2);  // inputs[:NN1] split image
    u16* imgMean = (u16*)alloc((size_t)MB1 * AIMG_STRIDE * 2);  // mean image (L0; L1 reuses)
    u16* imgH1   = (u16*)alloc((size_t)MB1 * AIMG_STRIDE * 2);  // h1 split image
    _Float16* h1h = (_Float16*)alloc((size_t)NN1 * DD * 2);     // row-linear fp16 h1 (gather1)
    u16* imgH2   = (u16*)alloc((size_t)MB2 * AIMG_STRIDE * 2);  // h2 split image
    // aliases (stream-ordered dead ranges):
    _Float16* xh = (_Float16*)imgH1;     // xh dead before gemm0 writes imgH1
    float* allout = (float*)imgX0;       // imgX0 dead after gemm0; head writes allout

    hipMemsetAsync(d_ws, 0, zero_bytes, stream);

    // CSR build, layer 0 and 1
    hist_kernel<<<(EE0 + 255) / 256, 256, 0, stream>>>(ed0, cnt0, EE0);
    hist_kernel<<<(EE1 + 255) / 256, 256, 0, stream>>>(ed1, cnt1, EE1);
    int nb0 = (NN1 + 1023) / 1024, nb1 = (NN2 + 1023) / 1024;
    scan_block_kernel<<<nb0, 256, 0, stream>>>(cnt0, rp0 + 1, part0, NN1);
    scan_partials_kernel<<<1, 256, 0, stream>>>(part0, nb0);
    scan_add_kernel<<<nb0, 256, 0, stream>>>(rp0 + 1, part0, NN1);
    scan_block_kernel<<<nb1, 256, 0, stream>>>(cnt1, rp1 + 1, part1, NN2);
    scan_partials_kernel<<<1, 256, 0, stream>>>(part1, nb1);
    scan_add_kernel<<<nb1, 256, 0, stream>>>(rp1 + 1, part1, NN2);
    fill_kernel<<<(EE0 + 255) / 256, 256, 0, stream>>>(es0, ed0, rp0, cur0, ss0, EE0);
    fill_kernel<<<(EE1 + 255) / 256, 256, 0, stream>>>(es1, ed1, rp1, cur1, ss1, EE1);

    // weight images (layers + head)
    build_wimg<<<64, 256, 0, stream>>>(Wself0, Wneigh0, Wself1, Wneigh1, wimg);
    build_wimg_head<<<48, 256, 0, stream>>>(Wp, Wpp, wimgH);

    // inputs: row-linear fp16 (gather) + tiled split image of rows < NN1 (gemm0 A0)
    long nx = (long)NN0 * DD;
    to_fp16_split<<<(int)(nx / 8 / 256), 256, 0, stream>>>(inputs, xh, imgX0, nx);

    // layer 0: gather writes mean split image; gemm consumes images, emits h1 image + h1h
    gather_mean_fp16<<<(NN1 + 3) / 4, 256, 0, stream>>>(xh, rp0, ss0, imgMean, NN1);
    dim3 g0(MB1, 2);
    gemm_img<<<g0, 256, 0, stream>>>(imgX0, imgMean, wimg, b0,
                                     nullptr, imgH1, h1h, NN1, DD, 1);

    // layer 1 (gather reads h1h; mean image buffer reused)
    gather_mean_fp16<<<(NN2 + 3) / 4, 256, 0, stream>>>(h1h, rp1, ss1, imgMean, NN2);
    dim3 g1(MB2, 2);
    gemm_img<<<g1, 256, 0, stream>>>(imgH1, imgMean, wimg + (size_t)32 * IMG_U16, b1,
                                     nullptr, imgH2, nullptr, NN2, DD, 1);

    // head as GEMM: [h2 | h1] @ [Wp|Wpp|0]^T -> allout, then select
    dim3 gh(MB2, 3);
    gemm_img<<<gh, 256, 0, stream>>>(imgH2, imgH1, wimgH, nullptr,
                                     allout, nullptr, nullptr, NN2, NHEAD, 0);
    select_kernel<<<(NN2 + 3) / 4, 256, 0, stream>>>(allout, (float*)d_out);
}